// Round 11
// baseline (84.322 us; speedup 1.0000x reference)
//
#include <hip/hip_runtime.h>
#include <math.h>

#define KK 49
#define H 128
#define W 128
#define C 64
#define NB 4
#define EPS 1e-7f
#define PLANE (H * W)

#define TW 32              // tile width (pixels)
#define TH 2               // tile height (pixels)
#define HW2 38             // halo width  = TW + 6
#define HH2 8              // halo height = TH + 6
#define NPOS (HW2 * HH2)   // 304 halo positions
#define CADDR (3 * HW2 + 3)// center offset within a thread's window base

// R11: SINGLE-PASS staging. R8->R10 cut LDS instrs 2x and barriers 2x with
// ~zero effect (kernel pinned at ~27-29 us) -> the wall is the pass-serialized
// load->vmcnt(0)->barrier->compute pipeline, not LDS/VALU throughput. So:
// stage ALL 64 channels as packed f16 in ONE buffer (8 grp x 304 pos x 16 B =
// 38.9 KB), one barrier, uninterrupted compute. Norms computed entirely in
// registers by slot owners (sn2 array + its barrier gone). Softmax combine
// buffers alias the dead sx region to stay <=40.96 KB -> 4 blocks/CU.
// v_dot2_f32_f16 compute; RTZ pack bias cancels in the cosine ratio (R10 ok).

typedef _Float16 h2_t __attribute__((ext_vector_type(2)));

__device__ __forceinline__ float fdot2(unsigned int a, unsigned int b, float c) {
    return __builtin_amdgcn_fdot2(__builtin_bit_cast(h2_t, a),
                                  __builtin_bit_cast(h2_t, b), c, false);
}
__device__ __forceinline__ unsigned int packh2(float a, float b) {
    return __builtin_bit_cast(unsigned int, __builtin_amdgcn_cvt_pkrtz(a, b));
}

template<int Q>
__device__ __forceinline__ void compute_q(const uint4* __restrict__ bp,
                                          float (&acc)[13]) {
    constexpr int NK = (Q == 3) ? 13 : 12;
    uint4 c[8];
#pragma unroll
    for (int g = 0; g < 8; ++g) c[g] = bp[g * NPOS + CADDR];
#pragma unroll
    for (int l = 0; l < NK; ++l) {
        const int k = Q * 12 + l;                    // compile-time after unroll
        const int off = (k / 7) * HW2 + (k % 7);
#pragma unroll
        for (int g = 0; g < 8; ++g) {
            const uint4 n = bp[g * NPOS + off];      // DS immediate offsets
            acc[l] = fdot2(c[g].x, n.x, acc[l]);
            acc[l] = fdot2(c[g].y, n.y, acc[l]);
            acc[l] = fdot2(c[g].z, n.z, acc[l]);
            acc[l] = fdot2(c[g].w, n.w, acc[l]);
        }
    }
}

template<int Q>
__device__ __forceinline__ void sim_and_max(const float* __restrict__ snb,
                                            float (&acc)[13], float& m) {
    constexpr int NK = (Q == 3) ? 13 : 12;
    const float nc = snb[CADDR];
#pragma unroll
    for (int l = 0; l < NK; ++l) {
        const int k = Q * 12 + l;
        const int off = (k / 7) * HW2 + (k % 7);
        const float nn = snb[off];
        const float sv = __fdividef(acc[l], nc * nn + EPS);
        acc[l] = sv;
        m = fmaxf(m, sv);
    }
}

template<int Q>
__device__ __forceinline__ void exp_and_sum(float (&acc)[13], float m, float& sum) {
    constexpr int NK = (Q == 3) ? 13 : 12;
#pragma unroll
    for (int l = 0; l < NK; ++l) {
        const float e = __expf(acc[l] - m);
        acc[l] = e;
        sum += e;
    }
}

template<int Q>
__device__ __forceinline__ void store_q(float* __restrict__ op,
                                        const float (&acc)[13], float inv) {
    constexpr int NK = (Q == 3) ? 13 : 12;
#pragma unroll
    for (int l = 0; l < NK; ++l)
        op[(size_t)l << 14] = acc[l] * inv;
}

#define DISPATCH_Q(stmt)                                      \
    do {                                                      \
        if (s2 == 0)      { constexpr int Q = 0; stmt; }      \
        else if (s2 == 1) { constexpr int Q = 1; stmt; }      \
        else if (s2 == 2) { constexpr int Q = 2; stmt; }      \
        else              { constexpr int Q = 3; stmt; }      \
    } while (0)

// 256 threads, tile 32x2, FOUR threads per pixel (k-quartered 7x7 window):
//   w = tid&31, r = (tid>>5)&1, s2 = tid>>6 (wave-uniform k-quarter).
// All wave LDS reads/writes and global stores are 32-lane-consecutive 16B/4B
// runs — proven conflict-free across R2..R10 (SQ_LDS_BANK_CONFLICT == 0).
// LAUNCH BOUNDS (hard-won): 2nd arg caps VGPRs at 256/arg on this toolchain
// (arg=4 -> 64-reg cap -> 500+MB scratch traffic, R4/R5). arg=2 -> 128 cap.
__global__ __launch_bounds__(256, 2) void rsa_kernel(const float* __restrict__ x,
                                                     float* __restrict__ out) {
    __shared__ uint4 sx[8 * NPOS];     // 38.9 KB: [grp][pos], 8 f16 ch per slot
    __shared__ float snf[NPOS];        // 1.2 KB : norms (written by slot owners)
    // softmax combine buffers alias sx (dead after the compute barrier)
    float* const combM = (float*)sx;         // 4*64 floats
    float* const combS = (float*)sx + 256;   // 4*64 floats

    const int tid = threadIdx.x;
    const int w   = tid & 31;
    const int r   = (tid >> 5) & 1;
    const int s2  = tid >> 6;          // wave-uniform (wave i -> s2 = i)
    const int w0  = blockIdx.x * TW;
    const int h0  = blockIdx.y * TH;
    const int b   = blockIdx.z;
    const float* __restrict__ xb = x + (size_t)b * C * PLANE;

    // thread's window-origin base (all window offsets become DS immediates)
    const int roww = r * HW2 + w;
    const uint4* const bp = &sx[0] + roww;

    // ---- single-pass staging: slot i owns halo position i, loads ALL 64 ch
#pragma unroll
    for (int j = 0; j < 2; ++j) {
        const int i = tid + j * 256;
        if (i < NPOS) {
            const int rr = i / HW2, cc = i - rr * HW2;
            const int gh = h0 - 3 + rr, gw = w0 - 3 + cc;
            float s = 0.f;
            if (gh >= 0 && gh < H && gw >= 0 && gw < W) {
                const float* p = xb + gh * W + gw;
#pragma unroll
                for (int g = 0; g < 8; ++g) {
                    float f0 = p[(size_t)(g * 8 + 0) * PLANE];
                    float f1 = p[(size_t)(g * 8 + 1) * PLANE];
                    float f2 = p[(size_t)(g * 8 + 2) * PLANE];
                    float f3 = p[(size_t)(g * 8 + 3) * PLANE];
                    float f4 = p[(size_t)(g * 8 + 4) * PLANE];
                    float f5 = p[(size_t)(g * 8 + 5) * PLANE];
                    float f6 = p[(size_t)(g * 8 + 6) * PLANE];
                    float f7 = p[(size_t)(g * 8 + 7) * PLANE];
                    uint4 u;
                    u.x = packh2(f0, f1);
                    u.y = packh2(f2, f3);
                    u.z = packh2(f4, f5);
                    u.w = packh2(f6, f7);
                    sx[g * NPOS + i] = u;
                    // norms from the SAME f16 values as the dot (bias cancels)
                    s = fdot2(u.x, u.x, s);
                    s = fdot2(u.y, u.y, s);
                    s = fdot2(u.z, u.z, s);
                    s = fdot2(u.w, u.w, s);
                }
            } else {
                const uint4 z = make_uint4(0u, 0u, 0u, 0u);
#pragma unroll
                for (int g = 0; g < 8; ++g) sx[g * NPOS + i] = z;
            }
            snf[i] = sqrtf(s);
        }
    }
    __syncthreads();   // the ONE main barrier

    // ---- uninterrupted compute: 112 ds_read_b128 + 416 dot2 per thread
    float acc[13];
#pragma unroll
    for (int l = 0; l < 13; ++l) acc[l] = 0.f;
    DISPATCH_Q(compute_q<Q>(bp, acc));

    // ---- cosine sim (snf only; sx dead after next barrier)
    const float* snb = &snf[0] + roww;
    float m = -1e30f;
    DISPATCH_Q(sim_and_max<Q>(snb, acc, m));

    __syncthreads();   // all sx reads complete -> alias region safe
    const int pxi = r * TW + w;
    combM[s2 * 64 + pxi] = m;
    __syncthreads();
    m = fmaxf(fmaxf(combM[0 * 64 + pxi], combM[1 * 64 + pxi]),
              fmaxf(combM[2 * 64 + pxi], combM[3 * 64 + pxi]));

    float sum = 0.f;
    DISPATCH_Q(exp_and_sum<Q>(acc, m, sum));
    combS[s2 * 64 + pxi] = sum;      // disjoint from combM, no barrier needed yet
    __syncthreads();
    sum = (combS[0 * 64 + pxi] + combS[1 * 64 + pxi]) +
          (combS[2 * 64 + pxi] + combS[3 * 64 + pxi]);
    const float inv = __fdividef(1.f, sum);

    float* op = out + (((size_t)b * KK + s2 * 12) << 14) + ((h0 + r) << 7) + (w0 + w);
    DISPATCH_Q(store_q<Q>(op, acc, inv));
}

extern "C" void kernel_launch(void* const* d_in, const int* in_sizes, int n_in,
                              void* d_out, int out_size, void* d_ws, size_t ws_size,
                              hipStream_t stream) {
    const float* x = (const float*)d_in[0];
    float* out = (float*)d_out;

    dim3 block(256, 1, 1);
    dim3 grid(W / TW, H / TH, NB);  // 4 x 64 x 4 = 1024 blocks (4 per CU, 16 waves/CU)
    rsa_kernel<<<grid, block, 0, stream>>>(x, out);
}

// Round 12
// 76.581 us; speedup vs baseline: 1.1011x; 1.1011x over previous
//
#include <hip/hip_runtime.h>
#include <math.h>

#define KK 49
#define H 128
#define W 128
#define C 64
#define NB 4
#define EPS 1e-7f
#define PLANE (H * W)

#define TW 32              // tile width (pixels)
#define TH 2               // tile height (pixels)
#define HW2 38             // halo width  = TW + 6
#define HH2 8              // halo height = TH + 6
#define NPOS (HW2 * HH2)   // 304 halo positions
#define NP2 (2 * NPOS)     // 608 slots per buffer (2 ch-8-groups of a pass)
#define CADDR (3 * HW2 + 3)// center offset within a thread's window base

// R12 = R10 (4-pass f16 double-buffer, 16 waves/CU) + XCD-BANDED SWIZZLE.
// R8-R11 varied LDS instrs (2x), barriers (8x), pass structure -> kernel
// pinned at 27-30 us. Remaining model: load phase ~8 us (FETCH 52 MB; the
// 268 MB d_ws poison fill evicts x from L3 each iter, and halo re-reads only
// hit if a same-XCD neighbor block fetched them into its 4 MB L2) + compute
// ~8 us + tail. Swizzle: id%8 -> XCD (round-robin heuristic), each XCD gets a
// contiguous 8-tile-row band per batch (~720 KB working set < 4 MB L2) so
// halo re-reads hit L2. Worst case (mapping wrong): neutral.

typedef _Float16 h2_t __attribute__((ext_vector_type(2)));

__device__ __forceinline__ float fdot2(unsigned int a, unsigned int b, float c) {
    return __builtin_amdgcn_fdot2(__builtin_bit_cast(h2_t, a),
                                  __builtin_bit_cast(h2_t, b), c, false);
}
__device__ __forceinline__ unsigned int packh2(float a, float b) {
    return __builtin_bit_cast(unsigned int, __builtin_amdgcn_cvt_pkrtz(a, b));
}

template<int Q>
__device__ __forceinline__ void compute_q(const uint4* __restrict__ bp,
                                          float (&acc)[13]) {
    constexpr int NK = (Q == 3) ? 13 : 12;
    const uint4 c0 = bp[CADDR];
    const uint4 c1 = bp[NPOS + CADDR];
#pragma unroll
    for (int l = 0; l < NK; ++l) {
        const int k = Q * 12 + l;                    // compile-time after unroll
        const int off = (k / 7) * HW2 + (k % 7);
        const uint4 n0 = bp[off];
        const uint4 n1 = bp[NPOS + off];
        acc[l] = fdot2(c0.x, n0.x, acc[l]);
        acc[l] = fdot2(c0.y, n0.y, acc[l]);
        acc[l] = fdot2(c0.z, n0.z, acc[l]);
        acc[l] = fdot2(c0.w, n0.w, acc[l]);
        acc[l] = fdot2(c1.x, n1.x, acc[l]);
        acc[l] = fdot2(c1.y, n1.y, acc[l]);
        acc[l] = fdot2(c1.z, n1.z, acc[l]);
        acc[l] = fdot2(c1.w, n1.w, acc[l]);
    }
}

template<int Q>
__device__ __forceinline__ void sim_and_max(const float* __restrict__ snb,
                                            float (&acc)[13], float& m) {
    constexpr int NK = (Q == 3) ? 13 : 12;
    const float nc = snb[CADDR];
#pragma unroll
    for (int l = 0; l < NK; ++l) {
        const int k = Q * 12 + l;
        const int off = (k / 7) * HW2 + (k % 7);
        const float nn = snb[off];
        const float sv = __fdividef(acc[l], nc * nn + EPS);
        acc[l] = sv;
        m = fmaxf(m, sv);
    }
}

template<int Q>
__device__ __forceinline__ void exp_and_sum(float (&acc)[13], float m, float& sum) {
    constexpr int NK = (Q == 3) ? 13 : 12;
#pragma unroll
    for (int l = 0; l < NK; ++l) {
        const float e = __expf(acc[l] - m);
        acc[l] = e;
        sum += e;
    }
}

template<int Q>
__device__ __forceinline__ void store_q(float* __restrict__ op,
                                        const float (&acc)[13], float inv) {
    constexpr int NK = (Q == 3) ? 13 : 12;
#pragma unroll
    for (int l = 0; l < NK; ++l)
        op[(size_t)l << 14] = acc[l] * inv;
}

#define DISPATCH_Q(stmt)                                      \
    do {                                                      \
        if (s2 == 0)      { constexpr int Q = 0; stmt; }      \
        else if (s2 == 1) { constexpr int Q = 1; stmt; }      \
        else if (s2 == 2) { constexpr int Q = 2; stmt; }      \
        else              { constexpr int Q = 3; stmt; }      \
    } while (0)

// 256 threads, tile 32x2, FOUR threads per pixel (k-quartered 7x7 window):
//   w = tid&31, r = (tid>>5)&1, s2 = tid>>6 (wave-uniform k-quarter).
// All wave LDS reads/writes and global stores are 32-lane-consecutive 16B/4B
// runs — proven conflict-free across R2..R11 (SQ_LDS_BANK_CONFLICT == 0).
// LAUNCH BOUNDS (hard-won): 2nd arg caps VGPRs at 256/arg on this toolchain
// (arg=4 -> 64-reg cap -> 500+MB scratch traffic, R4/R5). arg=2 -> 128 cap.
__global__ __launch_bounds__(256, 2) void rsa_kernel(const float* __restrict__ x,
                                                     float* __restrict__ out) {
    __shared__ uint4 sx[2][NP2];       // 19.0 KB: [buf][grp*NPOS + pos], 8 f16 ch
    __shared__ float sn2[NP2];         // 2.4 KB : per-8-group sum of squares
    __shared__ float snf[NPOS];        // 1.2 KB : final norms
    __shared__ float comb[4][TW * TH]; // 1.0 KB : softmax cross-quarter combine

    const int tid = threadIdx.x;
    const int w   = tid & 31;
    const int r   = (tid >> 5) & 1;
    const int s2  = tid >> 6;          // wave-uniform (wave i -> s2 = i)

    // ---- XCD-banded swizzle: id%8 = xcd; each xcd owns 8 contiguous tile-rows
    // per batch -> same-L2 blocks share halos (~720 KB band < 4 MB L2).
    const int id  = blockIdx.x;
    const int xcd = id & 7;
    const int seq = id >> 3;           // 0..127
    const int b   = seq >> 5;          // 0..3
    const int rem = seq & 31;
    const int ty  = xcd * 8 + (rem >> 2);  // 0..63
    const int tx  = rem & 3;               // 0..3
    const int w0  = tx * TW;
    const int h0  = ty * TH;
    const float* __restrict__ xb = x + (size_t)b * C * PLANE;

    // thread's window-origin bases (all window offsets become DS immediates)
    const int roww = r * HW2 + w;
    const uint4* const base4[2] = { &sx[0][0] + roww, &sx[1][0] + roww };

    // ---- staging slot metadata (fixed across passes): slot i = tid + 256*j
    int goff[3], pos[3], hh[3];
    bool act[3], inb[3];
#pragma unroll
    for (int j = 0; j < 3; ++j) {
        int i = tid + j * 256;
        act[j] = (i < NP2);
        int ii = act[j] ? i : 0;
        int g  = (ii >= NPOS) ? 1 : 0;
        int p  = ii - g * NPOS;
        int rr = p / HW2, cc = p - rr * HW2;
        int gh = h0 - 3 + rr, gw = w0 - 3 + cc;
        inb[j]  = (gh >= 0) && (gh < H) && (gw >= 0) && (gw < W);
        goff[j] = gh * W + gw;
        pos[j]  = ii;                  // flat slot index within one buffer
        hh[j]   = g;                   // channel-8-group of the pass
    }

    uint4 pu[3];
    float np[3] = {0.f, 0.f, 0.f};

    auto load_pass = [&](int t) {      // stage 16 channels: 2 groups of 8 (f16)
#pragma unroll
        for (int j = 0; j < 3; ++j) {
            uint4 u = make_uint4(0u, 0u, 0u, 0u);
            if (act[j] && inb[j]) {
                const float* p = xb + (size_t)(t * 16 + hh[j] * 8) * PLANE + goff[j];
                const float f0 = p[0];
                const float f1 = p[PLANE];
                const float f2 = p[2 * PLANE];
                const float f3 = p[3 * PLANE];
                const float f4 = p[4 * PLANE];
                const float f5 = p[5 * PLANE];
                const float f6 = p[6 * PLANE];
                const float f7 = p[7 * PLANE];
                u.x = packh2(f0, f1);
                u.y = packh2(f2, f3);
                u.z = packh2(f4, f5);
                u.w = packh2(f6, f7);
            }
            pu[j] = u;
        }
    };

    auto write_pass = [&](int buf) {
#pragma unroll
        for (int j = 0; j < 3; ++j) {
            if (act[j]) {
                sx[buf][pos[j]] = pu[j];
                // norms from the SAME f16 values as the dot -> RTZ bias cancels
                np[j] = fdot2(pu[j].x, pu[j].x, np[j]);
                np[j] = fdot2(pu[j].y, pu[j].y, np[j]);
                np[j] = fdot2(pu[j].z, pu[j].z, np[j]);
                np[j] = fdot2(pu[j].w, pu[j].w, np[j]);
            }
        }
    };

    float acc[13];
#pragma unroll
    for (int l = 0; l < 13; ++l) acc[l] = 0.f;

    // ---- software-pipelined main loop: 4 passes of 16 channels
    load_pass(0);
    write_pass(0);
    __syncthreads();
#pragma unroll
    for (int t = 0; t < 4; ++t) {
        const int buf = t & 1;
        if (t < 3) load_pass(t + 1);
        DISPATCH_Q(compute_q<Q>(base4[buf], acc));
        if (t < 3) write_pass(buf ^ 1);
        __syncthreads();
    }

    // ---- norms: slot owners hold per-8-group sums over all 4 passes
#pragma unroll
    for (int j = 0; j < 3; ++j)
        if (act[j]) sn2[pos[j]] = np[j];
    __syncthreads();
    for (int i = tid; i < NPOS; i += 256) snf[i] = sqrtf(sn2[i] + sn2[i + NPOS]);
    __syncthreads();

    // ---- cosine sim + cross-quarter softmax
    const float* snb = &snf[0] + roww;
    float m = -1e30f;
    DISPATCH_Q(sim_and_max<Q>(snb, acc, m));

    const int pxi = r * TW + w;
    comb[s2][pxi] = m;
    __syncthreads();
    m = fmaxf(fmaxf(comb[0][pxi], comb[1][pxi]), fmaxf(comb[2][pxi], comb[3][pxi]));
    __syncthreads();

    float sum = 0.f;
    DISPATCH_Q(exp_and_sum<Q>(acc, m, sum));
    comb[s2][pxi] = sum;
    __syncthreads();
    sum = (comb[0][pxi] + comb[1][pxi]) + (comb[2][pxi] + comb[3][pxi]);
    const float inv = __fdividef(1.f, sum);

    float* op = out + (((size_t)b * KK + s2 * 12) << 14) + ((h0 + r) << 7) + (w0 + w);
    DISPATCH_Q(store_q<Q>(op, acc, inv));
}

extern "C" void kernel_launch(void* const* d_in, const int* in_sizes, int n_in,
                              void* d_out, int out_size, void* d_ws, size_t ws_size,
                              hipStream_t stream) {
    const float* x = (const float*)d_in[0];
    float* out = (float*)d_out;

    dim3 block(256, 1, 1);
    dim3 grid(1024, 1, 1);  // flat; kernel decodes XCD-banded (b, ty, tx)
    rsa_kernel<<<grid, block, 0, stream>>>(x, out);
}

// Round 13
// 75.298 us; speedup vs baseline: 1.1198x; 1.0170x over previous
//
#include <hip/hip_runtime.h>
#include <math.h>

#define KK 49
#define H 128
#define W 128
#define C 64
#define NB 4
#define EPS 1e-7f
#define PLANE (H * W)

#define RW 32               // block region width (px)
#define RH 4                // block region height (px)
#define HWP 40              // halo array width : 38 used + 2 pad (B-tile reach)
#define HHP 12              // halo array height: 10 used + 2 pad
#define NPOS (HWP * HHP)    // 480 slots
#define TSTR 132            // transpose buffer stride (128 px + 4 bank-stagger)

// R13: Gram-matrix MFMA formulation. R12 confirmed L2-swizzle (+4.7 us); the
// remaining wall was the compute phase's ~1792 wave-b128/CU of LDS reads.
// Per wave: A-tile = 16 px (4x4 spatial), B-tiles = its 9 neighbor 4x4 tiles
// (12x12 super-tile); C = A.B^T via mfma_f32_16x16x32_f16, both operands
// loaded IDENTICALLY (pos=lane&15, ch-chunk=quad*8) from the same 8-ch-packed
// uint4 LDS slots — the m120-verified same-layout=>Gram recipe. 20 ds_read
// + 18 MFMA per wave replaces ~450 ds_reads. C-layout (col=lane&15,
// row=quad*4+reg): banded-window masks are pure lane geometry; per-px softmax
// = shfl_xor(1,2,4,8) within the quad. Stores go through an LDS transpose
// (aliased over dead sx) so each global store is a full 128-B line.
// f16 staging as R10/R12 (absmax 2.4e-4; bf16 would miss the 1.14e-3 bar).
// LAUNCH BOUNDS rule (R4/R5): 2nd arg caps VGPR at 256/arg -> (512,2) = 128.

typedef _Float16 h2_t __attribute__((ext_vector_type(2)));
typedef _Float16 v8h  __attribute__((ext_vector_type(8)));
typedef float    v4f  __attribute__((ext_vector_type(4)));

__device__ __forceinline__ float fdot2(unsigned int a, unsigned int b, float c) {
    return __builtin_amdgcn_fdot2(__builtin_bit_cast(h2_t, a),
                                  __builtin_bit_cast(h2_t, b), c, false);
}
__device__ __forceinline__ unsigned int packh2(float a, float b) {
    return __builtin_bit_cast(unsigned int, __builtin_amdgcn_cvt_pkrtz(a, b));
}

__global__ __launch_bounds__(512, 2) void rsa_kernel(const float* __restrict__ x,
                                                     float* __restrict__ out) {
    __shared__ uint4 sx[8 * NPOS];   // 61.4 KB: [grp][pos], 8 f16 ch per slot
    __shared__ float snf[NPOS];      // 1.9 KB : norms per halo position
    float* const trans = (float*)sx; // alias (sx dead after K-loop): 49*132*4=25.9KB

    const int tid = threadIdx.x;

    // ---- XCD-banded swizzle (R12-proven): xcd owns 4 contiguous tile-rows/batch
    const int id  = blockIdx.x;
    const int xcd = id & 7;
    const int seq = id >> 3;          // 0..63
    const int b   = seq >> 4;         // 0..3
    const int rem = seq & 15;
    const int by  = xcd * 4 + (rem >> 2);  // 0..31
    const int bx  = rem & 3;               // 0..3
    const int h0  = by * RH;
    const int w0  = bx * RW;
    const float* __restrict__ xb = x + (size_t)b * C * PLANE;

    // ---- staging: slot owner loads all 64 ch, packs f16, computes norm
    if (tid < NPOS) {
        const int hr = tid / HWP;          // 0..11
        const int hc = tid - hr * HWP;     // 0..39
        const int gh = h0 + hr - 3, gw = w0 + hc - 3;
        float s = 0.f;
        if (hr < 10 && hc < 38 && gh >= 0 && gh < H && gw >= 0 && gw < W) {
            const float* p = xb + gh * W + gw;
#pragma unroll
            for (int g = 0; g < 8; ++g) {
                const float* q = p + (size_t)(g * 8) * PLANE;
                uint4 u;
                u.x = packh2(q[0],         q[PLANE]);
                u.y = packh2(q[2 * PLANE], q[3 * PLANE]);
                u.z = packh2(q[4 * PLANE], q[5 * PLANE]);
                u.w = packh2(q[6 * PLANE], q[7 * PLANE]);
                sx[g * NPOS + tid] = u;
                s = fdot2(u.x, u.x, s);
                s = fdot2(u.y, u.y, s);
                s = fdot2(u.z, u.z, s);
                s = fdot2(u.w, u.w, s);
            }
        } else {
            const uint4 z = make_uint4(0u, 0u, 0u, 0u);
#pragma unroll
            for (int g = 0; g < 8; ++g) sx[g * NPOS + tid] = z;
        }
        snf[tid] = sqrtf(s);
    }
    __syncthreads();

    // ---- per-wave geometry: wave wv owns A-tile at cols tc*4 (tr = 0 only)
    const int lane = tid & 63;
    const int tc   = tid >> 6;        // 0..7 (wave index = A-tile col)
    const int quad = lane >> 4;       // ch-chunk for frags; px-row group for C
    const int l15  = lane & 15;
    const int sr   = l15 >> 2;        // spatial row within a 4x4 tile
    const int sc   = l15 & 3;         // spatial col within a 4x4 tile

    // A-frag: pos = px (l15) of this A-tile; k-chunk = quad*8 (+16t)
    const int apos = (sr + 3) * HWP + (tc * 4 + sc + 3);

    v4f acc[9];
#pragma unroll
    for (int f = 0; f < 9; ++f) acc[f] = (v4f)0.f;

#pragma unroll
    for (int t = 0; t < 2; ++t) {
        const int grp = 4 * t + quad;
        const v8h a = __builtin_bit_cast(v8h, sx[grp * NPOS + apos]);
#pragma unroll
        for (int dr = 0; dr < 3; ++dr) {
#pragma unroll
            for (int dc = 0; dc < 3; ++dc) {
                const int bpos = (dr * 4 + sr) * HWP + (tc * 4 + dc * 4 + sc);
                const v8h bb = __builtin_bit_cast(v8h, sx[grp * NPOS + bpos]);
                acc[dr * 3 + dc] =
                    __builtin_amdgcn_mfma_f32_16x16x32_f16(a, bb, acc[dr * 3 + dc], 0, 0, 0);
            }
        }
    }

    // ---- epilogue: C-layout col n = l15 (B pos), row m = quad*4 + reg (A px)
    float ncv[4];
#pragma unroll
    for (int r = 0; r < 4; ++r)
        ncv[r] = snf[(quad + 3) * HWP + (tc * 4 + r + 3)];
    float nnv[9];
#pragma unroll
    for (int f = 0; f < 9; ++f) {
        const int dr = f / 3, dc = f % 3;
        nnv[f] = snf[(dr * 4 + sr) * HWP + (tc * 4 + dc * 4 + sc)];
    }

    float mx[4] = {-1e30f, -1e30f, -1e30f, -1e30f};
#pragma unroll
    for (int f = 0; f < 9; ++f) {
        const int dr = f / 3, dc = f % 3;
        const int d0 = dr * 4 + sr - quad;       // window-row idx if in [0,6]
#pragma unroll
        for (int r = 0; r < 4; ++r) {
            const int de = dc * 4 + sc - r;      // window-col idx if in [0,6]
            const bool val = ((unsigned)d0 <= 6u) && ((unsigned)de <= 6u);
            const float sv = __fdividef(acc[f][r], ncv[r] * nnv[f] + EPS);
            acc[f][r] = sv;
            if (val) mx[r] = fmaxf(mx[r], sv);
        }
    }
#pragma unroll
    for (int wd = 1; wd < 16; wd <<= 1)
#pragma unroll
        for (int r = 0; r < 4; ++r)
            mx[r] = fmaxf(mx[r], __shfl_xor(mx[r], wd, 64));

    float sm[4] = {0.f, 0.f, 0.f, 0.f};
#pragma unroll
    for (int f = 0; f < 9; ++f) {
        const int dr = f / 3, dc = f % 3;
        const int d0 = dr * 4 + sr - quad;
#pragma unroll
        for (int r = 0; r < 4; ++r) {
            const int de = dc * 4 + sc - r;
            const bool val = ((unsigned)d0 <= 6u) && ((unsigned)de <= 6u);
            const float e = val ? __expf(acc[f][r] - mx[r]) : 0.f;
            acc[f][r] = e;
            sm[r] += e;
        }
    }
#pragma unroll
    for (int wd = 1; wd < 16; wd <<= 1)
#pragma unroll
        for (int r = 0; r < 4; ++r)
            sm[r] += __shfl_xor(sm[r], wd, 64);

    // ---- transpose through LDS (aliases sx) for full-line global stores
    __syncthreads();   // all sx (K-loop) reads complete before trans writes
#pragma unroll
    for (int r = 0; r < 4; ++r) {
        const float inv = __fdividef(1.f, sm[r]);
        const int px = quad * 32 + tc * 4 + r;   // local px index (row*32+col)
#pragma unroll
        for (int f = 0; f < 9; ++f) {
            const int dr = f / 3, dc = f % 3;
            const int d0 = dr * 4 + sr - quad;
            const int de = dc * 4 + sc - r;
            if (((unsigned)d0 <= 6u) && ((unsigned)de <= 6u)) {
                const int k = d0 * 7 + de;
                trans[k * TSTR + px] = acc[f][r] * inv;
            }
        }
    }
    __syncthreads();

    const size_t obase = ((size_t)b * KK) << 14;
#pragma unroll
    for (int j = 0; j < 13; ++j) {
        const int n = tid + j * 512;             // n = k*128 + px, n < 6272
        if (n < KK * 128) {
            const int k  = n >> 7;
            const int px = n & 127;
            const int gh = h0 + (px >> 5);
            const int gw = w0 + (px & 31);
            out[obase + ((size_t)k << 14) + (gh << 7) + gw] = trans[k * TSTR + px];
        }
    }
}

extern "C" void kernel_launch(void* const* d_in, const int* in_sizes, int n_in,
                              void* d_out, int out_size, void* d_ws, size_t ws_size,
                              hipStream_t stream) {
    const float* x = (const float*)d_in[0];
    float* out = (float*)d_out;

    dim3 block(512, 1, 1);
    dim3 grid(512, 1, 1);  // 2 blocks/CU, 16 waves/CU; XCD-banded decode inside
    rsa_kernel<<<grid, block, 0, stream>>>(x, out);
}

// Round 14
// 74.426 us; speedup vs baseline: 1.1330x; 1.0117x over previous
//
#include <hip/hip_runtime.h>
#include <math.h>

#define KK 49
#define H 128
#define W 128
#define C 64
#define NB 4
#define EPS 1e-7f
#define PLANE (H * W)

#define RW 32               // block region width (px)
#define RH 4                // block region height (px)
#define HWP 40              // halo array width : 38 used + 2 pad (B-tile reach)
#define HHP 12              // halo array height: 10 used + 2 pad
#define NPOS (HWP * HHP)    // 480 slots
#define TSTR 132            // transpose buffer stride (128 px + 4 bank-stagger)

// R14 = R13 (verified Gram-MFMA formulation, XCD swizzle, f16 staging) with
// the staging phase rebuilt around WIDE loads: R13 staged via 64 scalar
// global_load_dword per slot-owner in 8 serialized pack-groups (8 vmcnt
// round-trips); since w0 is 32-aligned, every 4-px float4 halo chunk is
// either fully in-image or fully out -> pure dwordx4 path, no edge scalars.
// Item = (ch-group g, halo row hr, chunk mi): 8 independent dwordx4 loads,
// 16 cvt_pkrtz, 4 ds_write_b128; 800 items/block, <=2/thread. Norms become a
// post-barrier LDS read-back (60 wave-b128). Unwritten slots are only pad
// rows 10-11 + (row9,col39), consumed exclusively by mask-discarded C
// entries -> garbage-safe, no zero-fill.
// MFMA: per wave A-tile = 16 px (4x4), 9 neighbor B-tiles, C = A.B^T via
// mfma_f32_16x16x32_f16, operands loaded identically from the 8-ch-packed
// uint4 slots (same-layout => Gram; R13-verified, absmax 2.4e-4).
// LAUNCH BOUNDS rule (R4/R5): 2nd arg caps VGPR at 256/arg -> (512,2) = 128.

typedef _Float16 h2_t __attribute__((ext_vector_type(2)));
typedef _Float16 v8h  __attribute__((ext_vector_type(8)));
typedef float    v4f  __attribute__((ext_vector_type(4)));

__device__ __forceinline__ float fdot2(unsigned int a, unsigned int b, float c) {
    return __builtin_amdgcn_fdot2(__builtin_bit_cast(h2_t, a),
                                  __builtin_bit_cast(h2_t, b), c, false);
}
__device__ __forceinline__ unsigned int packh2(float a, float b) {
    return __builtin_bit_cast(unsigned int, __builtin_amdgcn_cvt_pkrtz(a, b));
}

__global__ __launch_bounds__(512, 2) void rsa_kernel(const float* __restrict__ x,
                                                     float* __restrict__ out) {
    __shared__ uint4 sx[8 * NPOS];   // 61.4 KB: [grp][pos], 8 f16 ch per slot
    __shared__ float snf[NPOS];      // 1.9 KB : norms per halo position
    float* const trans = (float*)sx; // alias (sx dead after K-loop): 49*132*4=25.9KB

    const int tid = threadIdx.x;

    // ---- XCD-banded swizzle (R12-proven): xcd owns 4 contiguous tile-rows/batch
    const int id  = blockIdx.x;
    const int xcd = id & 7;
    const int seq = id >> 3;          // 0..63
    const int b   = seq >> 4;         // 0..3
    const int rem = seq & 15;
    const int by  = xcd * 4 + (rem >> 2);  // 0..31
    const int bx  = rem & 3;               // 0..3
    const int h0  = by * RH;
    const int w0  = bx * RW;
    const float* __restrict__ xb = x + (size_t)b * C * PLANE;

    // ---- staging: item = (g, hr, mi) -> 8 dwordx4 loads, pack, 4 b128 writes
#pragma unroll
    for (int j = 0; j < 2; ++j) {
        const int n = tid + j * 512;
        if (n < 800) {
            const int g   = n / 100;
            const int rm  = n - g * 100;
            const int hr  = rm / 10;
            const int mi  = rm - hr * 10;
            const int gh  = h0 + hr - 3;
            const int gw0 = w0 - 4 + 4 * mi;   // 16B-aligned (w0 % 32 == 0)
            const bool valid = (gh >= 0) && (gh < H) && (gw0 >= 0) && (gw0 + 3 < W);
            float4 va[8];
            if (valid) {
                const float* p = xb + (size_t)(8 * g) * PLANE + gh * W + gw0;
#pragma unroll
                for (int cc = 0; cc < 8; ++cc)
                    va[cc] = *(const float4*)(p + (size_t)cc * PLANE);
            } else {
#pragma unroll
                for (int cc = 0; cc < 8; ++cc)
                    va[cc] = make_float4(0.f, 0.f, 0.f, 0.f);
            }
#pragma unroll
            for (int e = 0; e < 4; ++e) {
                uint4 u;
                u.x = packh2(((const float*)&va[0])[e], ((const float*)&va[1])[e]);
                u.y = packh2(((const float*)&va[2])[e], ((const float*)&va[3])[e]);
                u.z = packh2(((const float*)&va[4])[e], ((const float*)&va[5])[e]);
                u.w = packh2(((const float*)&va[6])[e], ((const float*)&va[7])[e]);
                // slot col = 4*mi+e-1; col -1 wraps to prev row's pad col 39
                const int s = g * NPOS + hr * HWP + (4 * mi + e - 1);
                if (s >= 0) sx[s] = u;   // only (0,0,0,0) is s<0
            }
        }
    }
    __syncthreads();

    // ---- norms: read back each position's 8 packed slots
    if (tid < NPOS) {
        float sacc = 0.f;
#pragma unroll
        for (int g = 0; g < 8; ++g) {
            const uint4 u = sx[g * NPOS + tid];
            sacc = fdot2(u.x, u.x, sacc);
            sacc = fdot2(u.y, u.y, sacc);
            sacc = fdot2(u.z, u.z, sacc);
            sacc = fdot2(u.w, u.w, sacc);
        }
        snf[tid] = sqrtf(sacc);
    }
    __syncthreads();

    // ---- per-wave geometry: wave tc owns A-tile at cols tc*4
    const int lane = tid & 63;
    const int tc   = tid >> 6;        // 0..7 (wave index = A-tile col)
    const int quad = lane >> 4;       // ch-chunk for frags; px-row group for C
    const int l15  = lane & 15;
    const int sr   = l15 >> 2;        // spatial row within a 4x4 tile
    const int sc   = l15 & 3;         // spatial col within a 4x4 tile

    const int apos = (sr + 3) * HWP + (tc * 4 + sc + 3);

    v4f acc[9];
#pragma unroll
    for (int f = 0; f < 9; ++f) acc[f] = (v4f)0.f;

#pragma unroll
    for (int t = 0; t < 2; ++t) {
        const int grp = 4 * t + quad;
        const v8h a = __builtin_bit_cast(v8h, sx[grp * NPOS + apos]);
#pragma unroll
        for (int dr = 0; dr < 3; ++dr) {
#pragma unroll
            for (int dc = 0; dc < 3; ++dc) {
                const int bpos = (dr * 4 + sr) * HWP + (tc * 4 + dc * 4 + sc);
                const v8h bb = __builtin_bit_cast(v8h, sx[grp * NPOS + bpos]);
                acc[dr * 3 + dc] =
                    __builtin_amdgcn_mfma_f32_16x16x32_f16(a, bb, acc[dr * 3 + dc], 0, 0, 0);
            }
        }
    }

    // ---- epilogue: C-layout col n = l15 (B pos), row m = quad*4 + reg (A px)
    float ncv[4];
#pragma unroll
    for (int r = 0; r < 4; ++r)
        ncv[r] = snf[(quad + 3) * HWP + (tc * 4 + r + 3)];
    float nnv[9];
#pragma unroll
    for (int f = 0; f < 9; ++f) {
        const int dr = f / 3, dc = f % 3;
        nnv[f] = snf[(dr * 4 + sr) * HWP + (tc * 4 + dc * 4 + sc)];
    }

    float mx[4] = {-1e30f, -1e30f, -1e30f, -1e30f};
#pragma unroll
    for (int f = 0; f < 9; ++f) {
        const int dr = f / 3, dc = f % 3;
        const int d0 = dr * 4 + sr - quad;       // window-row idx if in [0,6]
#pragma unroll
        for (int r = 0; r < 4; ++r) {
            const int de = dc * 4 + sc - r;      // window-col idx if in [0,6]
            const bool val = ((unsigned)d0 <= 6u) && ((unsigned)de <= 6u);
            const float sv = __fdividef(acc[f][r], ncv[r] * nnv[f] + EPS);
            acc[f][r] = sv;
            if (val) mx[r] = fmaxf(mx[r], sv);
        }
    }
#pragma unroll
    for (int wd = 1; wd < 16; wd <<= 1)
#pragma unroll
        for (int r = 0; r < 4; ++r)
            mx[r] = fmaxf(mx[r], __shfl_xor(mx[r], wd, 64));

    float sm[4] = {0.f, 0.f, 0.f, 0.f};
#pragma unroll
    for (int f = 0; f < 9; ++f) {
        const int dr = f / 3, dc = f % 3;
        const int d0 = dr * 4 + sr - quad;
#pragma unroll
        for (int r = 0; r < 4; ++r) {
            const int de = dc * 4 + sc - r;
            const bool val = ((unsigned)d0 <= 6u) && ((unsigned)de <= 6u);
            const float e = val ? __expf(acc[f][r] - mx[r]) : 0.f;
            acc[f][r] = e;
            sm[r] += e;
        }
    }
#pragma unroll
    for (int wd = 1; wd < 16; wd <<= 1)
#pragma unroll
        for (int r = 0; r < 4; ++r)
            sm[r] += __shfl_xor(sm[r], wd, 64);

    // ---- transpose through LDS (aliases sx) for full-line global stores
    __syncthreads();   // all sx (K-loop) reads complete before trans writes
#pragma unroll
    for (int r = 0; r < 4; ++r) {
        const float inv = __fdividef(1.f, sm[r]);
        const int px = quad * 32 + tc * 4 + r;   // local px index (row*32+col)
#pragma unroll
        for (int f = 0; f < 9; ++f) {
            const int dr = f / 3, dc = f % 3;
            const int d0 = dr * 4 + sr - quad;
            const int de = dc * 4 + sc - r;
            if (((unsigned)d0 <= 6u) && ((unsigned)de <= 6u)) {
                const int k = d0 * 7 + de;
                trans[k * TSTR + px] = acc[f][r] * inv;
            }
        }
    }
    __syncthreads();

    const size_t obase = ((size_t)b * KK) << 14;
#pragma unroll
    for (int j = 0; j < 13; ++j) {
        const int n = tid + j * 512;             // n = k*128 + px, n < 6272
        if (n < KK * 128) {
            const int k  = n >> 7;
            const int px = n & 127;
            const int gh = h0 + (px >> 5);
            const int gw = w0 + (px & 31);
            out[obase + ((size_t)k << 14) + (gh << 7) + gw] = trans[k * TSTR + px];
        }
    }
}

extern "C" void kernel_launch(void* const* d_in, const int* in_sizes, int n_in,
                              void* d_out, int out_size, void* d_ws, size_t ws_size,
                              hipStream_t stream) {
    const float* x = (const float*)d_in[0];
    float* out = (float*)d_out;

    dim3 block(512, 1, 1);
    dim3 grid(512, 1, 1);  // 2 blocks/CU, 16 waves/CU; XCD-banded decode inside
    rsa_kernel<<<grid, block, 0, stream>>>(x, out);
}